// Round 11
// baseline (654.024 us; speedup 1.0000x reference)
//
#include <hip/hip_runtime.h>
#include <cstdint>
#include <cstddef>

#define N_NODES 100000
#define N_EDGES 1600000

// ---------------- workspace layout (byte offsets) ----------------
#define WS_ROWPTR   0            // (N+1) int
#define WS_DEG      400384       // N int
#define WS_FILL     800768       // N int
#define WS_INVDEG   1201152      // N float
#define WS_BSUM     1601536      // 98 int
#define WS_FLAG     1602560      // 1 int (1 = edge_index is int64)
#define WS_BP       1602816      // 4 x 64KB MFMA-frag-packed W (h 32KB + l 32KB each)
#define WS_BP2      1864960      // 40KB MFMA-frag-packed Wl2||Wr2 (hi 20KB + lo 20KB)
#define WS_COL      1906176      // E int
#define WS_AGG      8306432      // N*128 u32 pack (51.2MB)
#define WS_H1       59506432     // N*128 u32 pack
#define WS_P        WS_AGG              // overlay (agg dead after layer-1 GEMM); stride 64 f -> 25.6MB
#define WS_R        (WS_AGG + 25600000) // N*40 f (16MB; 25.6+16 < 51.2MB overlay)

typedef __attribute__((ext_vector_type(8))) short short8;
typedef __attribute__((ext_vector_type(4))) float floatx4;

// split fp32 into bf16 hi/lo, packed (hi in bits 31:16, lo bf16 bits in 15:0)
__device__ __forceinline__ unsigned pack_bf16x2(float x) {
    unsigned u = __float_as_uint(x);
    unsigned hi = (u + 0x7FFFu + ((u >> 16) & 1u)) & 0xFFFF0000u;
    float r = x - __uint_as_float(hi);
    unsigned ur = __float_as_uint(r);
    unsigned lo = (ur + 0x7FFFu + ((ur >> 16) & 1u)) >> 16;
    return hi | lo;
}
// reconstruct: hi + lo (error ~2^-17 relative)
__device__ __forceinline__ float unpk(unsigned u) {
    return __uint_as_float(u & 0xFFFF0000u) + __uint_as_float(u << 16);
}

__device__ __forceinline__ int edge_val(const void* ei, long long idx, int m64) {
    return m64 ? (int)((const long long*)ei)[idx] : ((const int*)ei)[idx];
}

// detect int32 vs int64 edge_index: int64 -> all odd 32-bit words are zero
__global__ void k_detect(const void* __restrict__ ei, int* __restrict__ flag) {
    __shared__ int s_any;
    if (threadIdx.x == 0) s_any = 0;
    __syncthreads();
    const int* p = (const int*)ei;
    int any = 0;
    for (int j = 0; j < 8; ++j) any |= p[2 * (threadIdx.x * 8 + j) + 1];
    if (any) s_any = 1;
    __syncthreads();
    if (threadIdx.x == 0) *flag = (s_any == 0) ? 1 : 0;
}

// pack Wl0,Wr0,Wl1,Wr1 into MFMA B-fragment order, bf16 hi/lo planes.
// B[k][n] frag for 16x16x32: lane supplies n=lane&15, k=quad*8+j (j=0..7).
__global__ void k_packw(const float* __restrict__ Wl0, const float* __restrict__ Wr0,
                        const float* __restrict__ Wl1, const float* __restrict__ Wr1,
                        short* __restrict__ bp) {
    int t = blockIdx.x * 256 + threadIdx.x;     // 8192 tasks
    if (t >= 8192) return;
    int mat = t >> 11, rem = t & 2047;
    int kt = rem >> 9, nt = (rem >> 6) & 7, lane = rem & 63;
    const float* W = (mat == 0) ? Wl0 : (mat == 1) ? Wr0 : (mat == 2) ? Wl1 : Wr1;
    int n  = nt * 16 + (lane & 15);
    int kb = kt * 32 + (lane >> 4) * 8;
    short* dh = bp + mat * 32768 + ((size_t)(kt * 8 + nt) * 64 + lane) * 8;
    short* dl = dh + 16384;
    for (int j = 0; j < 8; ++j) {
        unsigned p = pack_bf16x2(W[n * 128 + kb + j]);  // W row-major [o][k]
        dh[j] = (short)(p >> 16);
        dl[j] = (short)(p & 0xFFFFu);
    }
}

// pack Wl2||Wr2 (80 outs x 128) into B-fragments, 5 n-tiles x 4 k-tiles,
// same layout convention as k_packw. hi plane 10240 shorts, lo follows.
__global__ void k_packw2(const float* __restrict__ Wl2, const float* __restrict__ Wr2,
                         short* __restrict__ bp2) {
    int t = blockIdx.x * 256 + threadIdx.x;     // 1280 tasks
    if (t >= 1280) return;
    int kt = t / 320, rem = t % 320;
    int nt = rem / 64, lane = rem % 64;
    int n  = nt * 16 + (lane & 15);             // out index 0..79
    int kb = kt * 32 + (lane >> 4) * 8;
    const float* W = (n < 40) ? (Wl2 + (size_t)n * 128) : (Wr2 + (size_t)(n - 40) * 128);
    short* dh = bp2 + ((size_t)(kt * 5 + nt) * 64 + lane) * 8;
    short* dl = dh + 10240;
    for (int j = 0; j < 8; ++j) {
        unsigned p = pack_bf16x2(W[kb + j]);
        dh[j] = (short)(p >> 16);
        dl[j] = (short)(p & 0xFFFFu);
    }
}

// 4 edges/thread (block covers 1024 consecutive edges, stride-256 for
// per-instruction coalescing) -> 4 independent latency chains per thread.
__global__ void k_hist(const void* __restrict__ ei, const int* __restrict__ flag,
                       int* __restrict__ deg) {
    int m = *flag;
    int base = blockIdx.x * 1024 + threadIdx.x;
    #pragma unroll
    for (int j = 0; j < 4; ++j) {
        int e = base + j * 256;
        if (e < N_EDGES) {
            int d = edge_val(ei, (long long)N_EDGES + e, m);
            atomicAdd(&deg[d], 1);
        }
    }
}

__global__ void k_scan1(const int* __restrict__ deg, int* __restrict__ bsum) {
    __shared__ int sd[256];
    int t = threadIdx.x;
    int i0 = blockIdx.x * 1024 + t * 4;
    int s = 0;
    #pragma unroll
    for (int j = 0; j < 4; ++j) if (i0 + j < N_NODES) s += deg[i0 + j];
    sd[t] = s; __syncthreads();
    for (int off = 128; off; off >>= 1) {
        if (t < off) sd[t] += sd[t + off];
        __syncthreads();
    }
    if (t == 0) bsum[blockIdx.x] = sd[0];
}

// parallel exclusive scan of the 98 block sums (one block, 128 threads).
__global__ void k_scan2(int* __restrict__ bsum, int* __restrict__ row_ptr, int nb) {
    __shared__ int sd[128];
    int t = threadIdx.x;
    int v = (t < nb) ? bsum[t] : 0;
    sd[t] = v; __syncthreads();
    for (int off = 1; off < 128; off <<= 1) {
        int x = 0;
        if (t >= off) x = sd[t - off];
        __syncthreads();
        sd[t] += x;
        __syncthreads();
    }
    if (t < nb) bsum[t] = sd[t] - v;          // exclusive prefix
    if (t == 127) row_ptr[N_NODES] = sd[127]; // grand total (padding adds 0)
}

// v11: also emits invd (deg already in registers; bit-identical to k_invdeg)
__global__ void k_scan3(const int* __restrict__ deg, const int* __restrict__ bsum,
                        int* __restrict__ row_ptr, float* __restrict__ invd) {
    __shared__ int sd[256];
    int t = threadIdx.x;
    int i0 = blockIdx.x * 1024 + t * 4;
    int v[4]; int s = 0;
    #pragma unroll
    for (int j = 0; j < 4; ++j) { v[j] = (i0 + j < N_NODES) ? deg[i0 + j] : 0; s += v[j]; }
    sd[t] = s; __syncthreads();
    for (int off = 1; off < 256; off <<= 1) {
        int x = 0;
        if (t >= off) x = sd[t - off];
        __syncthreads();
        sd[t] += x;
        __syncthreads();
    }
    int run = bsum[blockIdx.x] + sd[t] - s;
    #pragma unroll
    for (int j = 0; j < 4; ++j) {
        if (i0 + j < N_NODES) {
            row_ptr[i0 + j] = run;
            invd[i0 + j] = 1.0f / (float)(v[j] > 1 ? v[j] : 1);
        }
        run += v[j];
    }
}

// 4 edges/thread, independent chains
__global__ void k_scatter(const void* __restrict__ ei, const int* __restrict__ flag,
                          const int* __restrict__ row_ptr, int* __restrict__ fill,
                          int* __restrict__ col) {
    int m = *flag;
    int base = blockIdx.x * 1024 + threadIdx.x;
    #pragma unroll
    for (int j = 0; j < 4; ++j) {
        int e = base + j * 256;
        if (e < N_EDGES) {
            int s = edge_val(ei, e, m);
            int d = edge_val(ei, (long long)N_EDGES + e, m);
            int pos = row_ptr[d] + atomicAdd(&fill[d], 1);
            col[pos] = s;
        }
    }
}

// mean-aggregate packed rows: one wave per node, uint2 (2 packed cols) per lane
// (round-0/8 verified structure: 8-edge batches, 24 VGPR, ~74% occupancy)
__global__ __launch_bounds__(256) void k_aggregate(
    const unsigned* __restrict__ h, const int* __restrict__ rowp,
    const int* __restrict__ col, const float* __restrict__ invd,
    unsigned* __restrict__ agg) {
    int w = blockIdx.x * 4 + (threadIdx.x >> 6);
    if (w >= N_NODES) return;
    int lane = threadIdx.x & 63;
    const uint2* hp = (const uint2*)h;
    int beg = rowp[w], end = rowp[w + 1];
    float x = 0.f, y = 0.f;
    int e = beg;
    for (; e + 8 <= end; e += 8) {
        int s0 = col[e], s1 = col[e + 1], s2 = col[e + 2], s3 = col[e + 3];
        int s4 = col[e + 4], s5 = col[e + 5], s6 = col[e + 6], s7 = col[e + 7];
        uint2 a = hp[(size_t)s0 * 64 + lane];
        uint2 b = hp[(size_t)s1 * 64 + lane];
        uint2 c = hp[(size_t)s2 * 64 + lane];
        uint2 d = hp[(size_t)s3 * 64 + lane];
        uint2 a2 = hp[(size_t)s4 * 64 + lane];
        uint2 b2 = hp[(size_t)s5 * 64 + lane];
        uint2 c2 = hp[(size_t)s6 * 64 + lane];
        uint2 d2 = hp[(size_t)s7 * 64 + lane];
        x += (unpk(a.x) + unpk(b.x)) + (unpk(c.x) + unpk(d.x))
           + (unpk(a2.x) + unpk(b2.x)) + (unpk(c2.x) + unpk(d2.x));
        y += (unpk(a.y) + unpk(b.y)) + (unpk(c.y) + unpk(d.y))
           + (unpk(a2.y) + unpk(b2.y)) + (unpk(c2.y) + unpk(d2.y));
    }
    for (; e < end; ++e) {
        uint2 a = hp[(size_t)col[e] * 64 + lane];
        x += unpk(a.x); y += unpk(a.y);
    }
    float id = invd[w];
    ((uint2*)agg)[(size_t)w * 64 + lane] =
        make_uint2(pack_bf16x2(x * id), pack_bf16x2(y * id));
}

// layer-0 variant: gather raw fp32 x rows directly (same addresses/add order)
__global__ __launch_bounds__(256) void k_aggregate_x(
    const float* __restrict__ xin, const int* __restrict__ rowp,
    const int* __restrict__ col, const float* __restrict__ invd,
    unsigned* __restrict__ agg) {
    int w = blockIdx.x * 4 + (threadIdx.x >> 6);
    if (w >= N_NODES) return;
    int lane = threadIdx.x & 63;
    const float2* hp = (const float2*)xin;
    int beg = rowp[w], end = rowp[w + 1];
    float x = 0.f, y = 0.f;
    int e = beg;
    for (; e + 8 <= end; e += 8) {
        int s0 = col[e], s1 = col[e + 1], s2 = col[e + 2], s3 = col[e + 3];
        int s4 = col[e + 4], s5 = col[e + 5], s6 = col[e + 6], s7 = col[e + 7];
        float2 a = hp[(size_t)s0 * 64 + lane];
        float2 b = hp[(size_t)s1 * 64 + lane];
        float2 c = hp[(size_t)s2 * 64 + lane];
        float2 d = hp[(size_t)s3 * 64 + lane];
        float2 a2 = hp[(size_t)s4 * 64 + lane];
        float2 b2 = hp[(size_t)s5 * 64 + lane];
        float2 c2 = hp[(size_t)s6 * 64 + lane];
        float2 d2 = hp[(size_t)s7 * 64 + lane];
        x += (a.x + b.x) + (c.x + d.x) + (a2.x + b2.x) + (c2.x + d2.x);
        y += (a.y + b.y) + (c.y + d.y) + (a2.y + b2.y) + (c2.y + d2.y);
    }
    for (; e < end; ++e) {
        float2 a = hp[(size_t)col[e] * 64 + lane];
        x += a.x; y += a.y;
    }
    float id = invd[w];
    ((uint2*)agg)[(size_t)w * 64 + lane] =
        make_uint2(pack_bf16x2(x * id), pack_bf16x2(y * id));
}

// bf16x3 MFMA GEMM: out = relu(l2norm(agg@WlT + h@WrT + b)), packed u32 I/O.
// v9 structure: B panels LDS-double-buffered AND A fragments register-
// prefetched one panel ahead. Bit-identical numerics to v6-v10.
// v11 FUSE2: layer-2 GEMM fused into the epilogue — A-carriers read from the
// per-wave LDS tile (byte-identical to the h2 rows gemm2_mfma read from
// global), B2 fragments from global bp2 (40KB, L2-broadcast), same MFMA order
// as k_gemm2_mfma -> bit-identical P/R; h2 never touches global memory.
template<bool F32H, bool FUSE2>
__global__ __launch_bounds__(256) void k_gemm_mfma(
    const unsigned* __restrict__ Vpack, const void* __restrict__ Hsrc,
    const short* __restrict__ BL, const short* __restrict__ BR,
    const float* __restrict__ bias, unsigned* __restrict__ outp,
    const short* __restrict__ bp2, const float* __restrict__ b2,
    float* __restrict__ P, float* __restrict__ R) {
    __shared__ unsigned sE[4 * 2048];   // 32 KB: 2x16KB B panels; epilogue 8KB/wave
    const int t = threadIdx.x, lane = t & 63, wv = t >> 6;
    const int mrow = lane & 15, kq = lane >> 4;
    int nb = blockIdx.x * 64 + wv * 16;
    if (nb > N_NODES - 16) nb = N_NODES - 16;   // tail: duplicate recompute, benign

    floatx4 acc[8];
    #pragma unroll
    for (int nt = 0; nt < 8; ++nt) {
        float bv = bias[nt * 16 + mrow];
        floatx4 b4 = {bv, bv, bv, bv};
        acc[nt] = b4;
    }

    const size_t rbase = (size_t)(nb + mrow) * 128 + kq * 8;
    uint4* sB = (uint4*)sE;                   // buf0: uint4[0..1023], buf1: [1024..2047]
    uint4 a0c, a1c;
    {
        const uint4* gh = (const uint4*)BL;
        const uint4* gl = (const uint4*)(BL + 16384);
        uint4 r0 = gh[t], r1 = gh[t + 256], r2 = gl[t], r3 = gl[t + 256];
        const unsigned* ap = Vpack + rbase;
        a0c = *(const uint4*)ap; a1c = *(const uint4*)(ap + 4);
        sB[t] = r0; sB[t + 256] = r1; sB[t + 512] = r2; sB[t + 768] = r3;
    }
    __syncthreads();

    #pragma unroll
    for (int p = 0; p < 8; ++p) {
        const int ph = p >> 2;
        uint4 r0, r1, r2, r3, a0n, a1n;
        if (p < 7) {
            const int pn = p + 1, phn = pn >> 2, ktn = pn & 3;
            const short* Bs = phn ? BR : BL;
            const uint4* gh = (const uint4*)(Bs + ktn * 4096);
            const uint4* gl = (const uint4*)(Bs + 16384 + ktn * 4096);
            r0 = gh[t]; r1 = gh[t + 256]; r2 = gl[t]; r3 = gl[t + 256];
            const size_t roffn = rbase + ktn * 32;
            if (F32H && phn == 1) {
                const float* fp = (const float*)Hsrc + roffn;
                a0n = *(const uint4*)fp; a1n = *(const uint4*)(fp + 4);
            } else {
                const unsigned* ap = (phn ? (const unsigned*)Hsrc : Vpack) + roffn;
                a0n = *(const uint4*)ap; a1n = *(const uint4*)(ap + 4);
            }
        }
        short8 Ah, Al;
        {
            unsigned ua[8] = {a0c.x, a0c.y, a0c.z, a0c.w, a1c.x, a1c.y, a1c.z, a1c.w};
            if (F32H && ph == 1) {
                #pragma unroll
                for (int j = 0; j < 8; ++j) {
                    unsigned pk = pack_bf16x2(__uint_as_float(ua[j]));
                    Ah[j] = (short)(pk >> 16);
                    Al[j] = (short)(pk & 0xFFFFu);
                }
            } else {
                #pragma unroll
                for (int j = 0; j < 8; ++j) {
                    Ah[j] = (short)(ua[j] >> 16);
                    Al[j] = (short)(ua[j] & 0xFFFFu);
                }
            }
        }
        const short8* sBc = (const short8*)(sB + (p & 1) * 1024);
        #pragma unroll
        for (int nt = 0; nt < 8; ++nt) {
            short8 bh = sBc[nt * 64 + lane];
            short8 bl = sBc[512 + nt * 64 + lane];
            acc[nt] = __builtin_amdgcn_mfma_f32_16x16x32_bf16(Ah, bh, acc[nt], 0, 0, 0);
            acc[nt] = __builtin_amdgcn_mfma_f32_16x16x32_bf16(Ah, bl, acc[nt], 0, 0, 0);
            acc[nt] = __builtin_amdgcn_mfma_f32_16x16x32_bf16(Al, bh, acc[nt], 0, 0, 0);
        }
        if (p < 7) {
            __syncthreads();
            uint4* sBn = sB + ((p + 1) & 1) * 1024;
            sBn[t] = r0; sBn[t + 256] = r1; sBn[t + 512] = r2; sBn[t + 768] = r3;
            a0c = a0n; a1c = a1n;
            __syncthreads();
        }
    }
    __syncthreads();

    // epilogue: l2norm rows, relu, pack into per-wave LDS tile (16 x 128 u32)
    unsigned* myE = sE + wv * 2048;
    float ss[4] = {0.f, 0.f, 0.f, 0.f};
    #pragma unroll
    for (int nt = 0; nt < 8; ++nt)
        #pragma unroll
        for (int r = 0; r < 4; ++r) ss[r] += acc[nt][r] * acc[nt][r];
    #pragma unroll
    for (int m = 1; m < 16; m <<= 1) {
        #pragma unroll
        for (int r = 0; r < 4; ++r) ss[r] += __shfl_xor(ss[r], m, 64);
    }
    float sc[4];
    #pragma unroll
    for (int r = 0; r < 4; ++r) sc[r] = 1.f / fmaxf(sqrtf(ss[r]), 1e-12f);
    #pragma unroll
    for (int nt = 0; nt < 8; ++nt)
        #pragma unroll
        for (int r = 0; r < 4; ++r) {
            float v = fmaxf(acc[nt][r] * sc[r], 0.f);
            myE[(kq * 4 + r) * 128 + nt * 16 + mrow] = pack_bf16x2(v);
        }
    __builtin_amdgcn_wave_barrier();

    if constexpr (!FUSE2) {
        // store h tile to global (layer-0 path)
        #pragma unroll
        for (int i = 0; i < 8; ++i) {
            int row = i * 2 + (lane >> 5);
            int colw = (lane & 31) * 4;
            uint4 d = *(const uint4*)(myE + row * 128 + colw);
            *(uint4*)(outp + (size_t)(nb + row) * 128 + colw) = d;
        }
    } else {
        // fused layer-2: [P|R](80) = h2 @ [Wl2|Wr2]^T (+b2 on R side).
        // A-carriers from myE (bit-identical to h2p rows); B2 from global
        // (L2-hot); same kt -> nt -> {hh,hl,lh} order as k_gemm2_mfma.
        floatx4 acc2[5];
        #pragma unroll
        for (int nt = 0; nt < 5; ++nt) {
            int o = nt * 16 + mrow;
            float bv = (o >= 40) ? b2[o - 40] : 0.f;
            floatx4 b4 = {bv, bv, bv, bv};
            acc2[nt] = b4;
        }
        const unsigned* aRow = myE + mrow * 128 + kq * 8;
        const short8* g8 = (const short8*)bp2;
        #pragma unroll
        for (int kt = 0; kt < 4; ++kt) {
            uint4 c0 = *(const uint4*)(aRow + kt * 32);
            uint4 c1 = *(const uint4*)(aRow + kt * 32 + 4);
            short8 Ah2, Al2;
            unsigned ua[8] = {c0.x, c0.y, c0.z, c0.w, c1.x, c1.y, c1.z, c1.w};
            #pragma unroll
            for (int j = 0; j < 8; ++j) {
                Ah2[j] = (short)(ua[j] >> 16);
                Al2[j] = (short)(ua[j] & 0xFFFFu);
            }
            #pragma unroll
            for (int nt = 0; nt < 5; ++nt) {
                short8 bh = g8[(size_t)(kt * 5 + nt) * 64 + lane];
                short8 bl = g8[1280 + (size_t)(kt * 5 + nt) * 64 + lane];
                acc2[nt] = __builtin_amdgcn_mfma_f32_16x16x32_bf16(Ah2, bh, acc2[nt], 0, 0, 0);
                acc2[nt] = __builtin_amdgcn_mfma_f32_16x16x32_bf16(Ah2, bl, acc2[nt], 0, 0, 0);
                acc2[nt] = __builtin_amdgcn_mfma_f32_16x16x32_bf16(Al2, bh, acc2[nt], 0, 0, 0);
            }
        }
        __builtin_amdgcn_wave_barrier();   // myE A-reads done; safe to overwrite
        float* sT = (float*)myE;           // 16 nodes x 80 outs (5120B < 8KB)
        #pragma unroll
        for (int nt = 0; nt < 5; ++nt)
            #pragma unroll
            for (int r = 0; r < 4; ++r)
                sT[(kq * 4 + r) * 80 + nt * 16 + mrow] = acc2[nt][r];
        __builtin_amdgcn_wave_barrier();
        #pragma unroll
        for (int i = 0; i < 5; ++i) {
            int idx = i * 64 + lane;       // 0..319
            int node = idx / 20, q = idx % 20;
            float4 v = *(const float4*)(sT + node * 80 + q * 4);
            if (q < 10) *(float4*)(P + (size_t)(nb + node) * 64 + q * 4) = v;
            else        *(float4*)(R + (size_t)(nb + node) * 40 + (q - 10) * 4) = v;
        }
    }
}

// final: logits = mean_agg(P[src]) + R; softmax over 40; one wave per node.
// 8 edges per iteration (8 loads in flight) with 8 accumulators.
// P rows stride-64 (256B aligned, 2 lines).
__global__ __launch_bounds__(256) void k_final(
    const float* __restrict__ P, const float* __restrict__ R,
    const int* __restrict__ rowp, const int* __restrict__ col,
    const float* __restrict__ invd, float* __restrict__ out) {
    int w = blockIdx.x * 4 + (threadIdx.x >> 6);
    if (w >= N_NODES) return;
    int lane = threadIdx.x & 63;
    bool act = lane < 40;
    int beg = rowp[w], end = rowp[w + 1];
    float a0 = 0.f, a1 = 0.f, a2 = 0.f, a3 = 0.f;
    float a4 = 0.f, a5 = 0.f, a6 = 0.f, a7 = 0.f;
    int e = beg;
    for (; e + 8 <= end; e += 8) {
        int s0 = col[e],     s1 = col[e + 1], s2 = col[e + 2], s3 = col[e + 3];
        int s4 = col[e + 4], s5 = col[e + 5], s6 = col[e + 6], s7 = col[e + 7];
        if (act) {
            float f0 = P[(size_t)s0 * 64 + lane];
            float f1 = P[(size_t)s1 * 64 + lane];
            float f2 = P[(size_t)s2 * 64 + lane];
            float f3 = P[(size_t)s3 * 64 + lane];
            float f4 = P[(size_t)s4 * 64 + lane];
            float f5 = P[(size_t)s5 * 64 + lane];
            float f6 = P[(size_t)s6 * 64 + lane];
            float f7 = P[(size_t)s7 * 64 + lane];
            a0 += f0; a1 += f1; a2 += f2; a3 += f3;
            a4 += f4; a5 += f5; a6 += f6; a7 += f7;
        }
    }
    for (; e + 4 <= end; e += 4) {
        int s0 = col[e], s1 = col[e + 1], s2 = col[e + 2], s3 = col[e + 3];
        if (act) {
            a0 += P[(size_t)s0 * 64 + lane];
            a1 += P[(size_t)s1 * 64 + lane];
            a2 += P[(size_t)s2 * 64 + lane];
            a3 += P[(size_t)s3 * 64 + lane];
        }
    }
    for (; e < end; ++e) if (act) a0 += P[(size_t)col[e] * 64 + lane];
    float acc = ((a0 + a1) + (a2 + a3)) + ((a4 + a5) + (a6 + a7));
    float v = act ? (acc * invd[w] + R[(size_t)w * 40 + lane]) : -1e30f;
    float m = v;
    #pragma unroll
    for (int off = 32; off; off >>= 1) m = fmaxf(m, __shfl_xor(m, off, 64));
    float ex = act ? expf(v - m) : 0.f;
    float s = ex;
    #pragma unroll
    for (int off = 32; off; off >>= 1) s += __shfl_xor(s, off, 64);
    if (act) out[(size_t)w * 40 + lane] = ex / s;
}

extern "C" void kernel_launch(void* const* d_in, const int* in_sizes, int n_in,
                              void* d_out, int out_size, void* d_ws, size_t ws_size,
                              hipStream_t stream) {
    const float* x   = (const float*)d_in[0];
    const void*  ei  = d_in[1];
    const float* Wl0 = (const float*)d_in[2];
    const float* Wr0 = (const float*)d_in[3];
    const float* b0  = (const float*)d_in[4];
    const float* Wl1 = (const float*)d_in[5];
    const float* Wr1 = (const float*)d_in[6];
    const float* b1  = (const float*)d_in[7];
    const float* Wl2 = (const float*)d_in[8];
    const float* Wr2 = (const float*)d_in[9];
    const float* b2  = (const float*)d_in[10];
    float* out = (float*)d_out;

    char* ws = (char*)d_ws;
    int*      row_ptr = (int*)(ws + WS_ROWPTR);
    int*      deg     = (int*)(ws + WS_DEG);
    int*      fill    = (int*)(ws + WS_FILL);
    float*    invd    = (float*)(ws + WS_INVDEG);
    int*      bsum    = (int*)(ws + WS_BSUM);
    int*      flag    = (int*)(ws + WS_FLAG);
    short*    bp      = (short*)(ws + WS_BP);
    short*    bp2     = (short*)(ws + WS_BP2);
    int*      col     = (int*)(ws + WS_COL);
    unsigned* aggp    = (unsigned*)(ws + WS_AGG);
    unsigned* h1p     = (unsigned*)(ws + WS_H1);
    float*    P       = (float*)(ws + WS_P);
    float*    R       = (float*)(ws + WS_R);

    hipMemsetAsync(ws + WS_DEG, 0, 800768, stream);

    k_detect<<<1, 256, 0, stream>>>(ei, flag);
    k_packw<<<32, 256, 0, stream>>>(Wl0, Wr0, Wl1, Wr1, bp);
    k_packw2<<<5, 256, 0, stream>>>(Wl2, Wr2, bp2);
    k_hist<<<1563, 256, 0, stream>>>(ei, flag, deg);
    k_scan1<<<98, 256, 0, stream>>>(deg, bsum);
    k_scan2<<<1, 128, 0, stream>>>(bsum, row_ptr, 98);
    k_scan3<<<98, 256, 0, stream>>>(deg, bsum, row_ptr, invd);
    k_scatter<<<1563, 256, 0, stream>>>(ei, flag, row_ptr, fill, col);

    // layer 0 (x consumed directly in fp32: no pack_x round-trip)
    k_aggregate_x<<<25000, 256, 0, stream>>>(x, row_ptr, col, invd, aggp);
    k_gemm_mfma<true, false><<<1563, 256, 0, stream>>>(
        aggp, (const void*)x, bp, bp + 32768, b0, h1p, nullptr, nullptr, nullptr, nullptr);
    // layer 1 + fused layer 2 (h2 never hits global; P/R written directly)
    k_aggregate<<<25000, 256, 0, stream>>>(h1p, row_ptr, col, invd, aggp);
    k_gemm_mfma<false, true><<<1563, 256, 0, stream>>>(
        aggp, (const void*)h1p, bp + 2 * 32768, bp + 3 * 32768, b1, nullptr, bp2, b2, P, R);
    // final: aggregate the 40-dim projections + softmax
    k_final<<<25000, 256, 0, stream>>>(P, R, row_ptr, col, invd, out);
}